// Round 5
// baseline (869.780 us; speedup 1.0000x reference)
//
#include <hip/hip_runtime.h>
#include <hip/hip_fp16.h>
#include <math.h>

#define D 64
#define WAVE 64
#define TILE 128   // nodes per block in proj (LDS = 128*64*4 = 32 KB)

// ---------- helpers ----------
__device__ __forceinline__ float wave_reduce_sum(float v) {
    v += __shfl_xor(v, 32);
    v += __shfl_xor(v, 16);
    v += __shfl_xor(v, 8);
    v += __shfl_xor(v, 4);
    v += __shfl_xor(v, 2);
    v += __shfl_xor(v, 1);
    return v;
}

__device__ __forceinline__ float wave_reduce_max(float v) {
    v = fmaxf(v, __shfl_xor(v, 32));
    v = fmaxf(v, __shfl_xor(v, 16));
    v = fmaxf(v, __shfl_xor(v, 8));
    v = fmaxf(v, __shfl_xor(v, 4));
    v = fmaxf(v, __shfl_xor(v, 2));
    v = fmaxf(v, __shfl_xor(v, 1));
    return v;
}

__device__ __forceinline__ float fast_tanh(float x) {
    // tanh(x) = 1 - 2/(exp(2x)+1); saturates correctly at +-1 (inf-safe)
    float e = __expf(2.0f * x);
    return 1.0f - 2.0f / (e + 1.0f);
}

// ---------- 1. proj[n][r][o] = sum_i nfeat[n][i] * W[r][i][o]  (fp16 out) ----------
// One block = 128-node tile staged in LDS ONCE; all 10 relations computed from
// it (kills the 10x nfeat HBM re-read seen in rocprof: FETCH 245MB -> ~30MB).
// Wave w owns nodes [w*32, w*32+32). Per relation: W_r column in 64 VGPRs,
// x via broadcast ds_read_b128 (uniform addr -> conflict-free), 4 FMA chains.
__global__ __launch_bounds__(256) void proj_kernel(
    const float* __restrict__ nfeat, const float* __restrict__ W,
    __half* __restrict__ proj, int n_nodes, int n_rel) {
    __shared__ float xs[TILE][D];
    const int tid = threadIdx.x;
    const int lane = tid & 63;
    const int wid = tid >> 6;
    const int n0 = blockIdx.x * TILE;

    // stage tile, coalesced float4 (2048 float4s / 256 threads = 8 iters)
    const float4* g4 = (const float4*)(nfeat + (size_t)n0 * D);
    float4* s4 = (float4*)(&xs[0][0]);
    int avail_rows = n_nodes - n0;
    if (avail_rows > TILE) avail_rows = TILE;
    const int avail4 = avail_rows * (D / 4);
#pragma unroll
    for (int i = tid; i < TILE * (D / 4); i += 256) {
        s4[i] = (i < avail4) ? g4[i] : make_float4(0.f, 0.f, 0.f, 0.f);
    }
    __syncthreads();

    const int nloc0 = wid * (TILE / 4);  // 32 nodes per wave
    for (int r = 0; r < n_rel; ++r) {
        float w[D];
        const float* Wr = W + (size_t)r * D * D;
#pragma unroll
        for (int i = 0; i < D; ++i) w[i] = Wr[i * D + lane];  // coalesced, L2-hot
        for (int k = 0; k < TILE / 4; ++k) {
            const int n = n0 + nloc0 + k;
            if (n >= n_nodes) break;  // wave-uniform
            const float4* x4 = (const float4*)(&xs[nloc0 + k][0]);
            float a0 = 0.f, a1 = 0.f, a2 = 0.f, a3 = 0.f;
#pragma unroll
            for (int i = 0; i < D / 4; ++i) {
                float4 xv = x4[i];  // broadcast ds_read_b128
                a0 = fmaf(xv.x, w[4 * i + 0], a0);
                a1 = fmaf(xv.y, w[4 * i + 1], a1);
                a2 = fmaf(xv.z, w[4 * i + 2], a2);
                a3 = fmaf(xv.w, w[4 * i + 3], a3);
            }
            proj[((size_t)n * n_rel + r) * D + lane] =
                __float2half_rn((a0 + a1) + (a2 + a3));
        }
    }
}

// ---------- 2. att[e] = sum_d t_r[d] * tanh(h_r[d] + efeat[e][d]) ----------
// 4 edges per wave, 16 lanes per edge, 4 channels per lane:
// efeat via float4 (16B/lane), proj via 16B of halves, 4-step reduce.
__global__ __launch_bounds__(256) void att_kernel(
    const __half* __restrict__ proj, const float* __restrict__ efeat,
    const int* __restrict__ src, const int* __restrict__ dst,
    const int* __restrict__ etype, float* __restrict__ att,
    int n_edges, int n_rel) {
    const int lane = threadIdx.x & 63;
    const int wid = threadIdx.x >> 6;
    const int g = lane >> 4;       // edge slot 0..3 within wave
    const int c4 = lane & 15;      // float4 chunk of the row

    int e = (blockIdx.x * 4 + wid) * 4 + g;
    const bool valid = e < n_edges;
    const int ec = valid ? e : (n_edges - 1);
    const int s = src[ec];
    const int d = dst[ec];
    const int et = etype[ec];

    const float4* ef4 = (const float4*)(efeat + (size_t)ec * D);
    float4 ef = ef4[c4];
    const __half2* tp = (const __half2*)(proj + ((size_t)s * n_rel + et) * D) + c4 * 2;
    const __half2* hp = (const __half2*)(proj + ((size_t)d * n_rel + et) * D) + c4 * 2;
    float2 tA = __half22float2(tp[0]);
    float2 tB = __half22float2(tp[1]);
    float2 hA = __half22float2(hp[0]);
    float2 hB = __half22float2(hp[1]);

    float v = tA.x * fast_tanh(hA.x + ef.x)
            + tA.y * fast_tanh(hA.y + ef.y)
            + tB.x * fast_tanh(hB.x + ef.z)
            + tB.y * fast_tanh(hB.y + ef.w);
    v += __shfl_xor(v, 8);
    v += __shfl_xor(v, 4);
    v += __shfl_xor(v, 2);
    v += __shfl_xor(v, 1);
    if (valid && c4 == 0) att[e] = v;
}

// ---------- 3. CSR row_ptr from sorted dst ----------
__global__ void rowptr_kernel(const int* __restrict__ dst, int* __restrict__ row_ptr,
                              int n_edges, int n_nodes) {
    int tid = blockIdx.x * blockDim.x + threadIdx.x;
    int stride = gridDim.x * blockDim.x;
    for (int e = tid; e < n_edges; e += stride) {
        int d = dst[e];
        int dprev = (e == 0) ? -1 : dst[e - 1];
        for (int v = dprev + 1; v <= d; ++v) row_ptr[v] = e;
    }
    if (tid == 0) {
        int dlast = dst[n_edges - 1];
        for (int v = dlast + 1; v <= n_nodes; ++v) row_ptr[v] = n_edges;
    }
}

// ---------- 4. fused edge-softmax + weighted aggregation ----------
// Wave per node. h_nb[n] = (sum_j ex_j * nfeat[src_j]) / (sum_j ex_j).
// Inner j-loop unrolled x4 with 4 acc chains + 4 gathers in flight; padded
// lanes have ex=0 so no tail guards needed (fma adds 0).
__global__ __launch_bounds__(256) void agg_kernel(
    const float* __restrict__ att, const int* __restrict__ src,
    const int* __restrict__ row_ptr, const float* __restrict__ nfeat,
    float* __restrict__ h_nb, int n_nodes) {
    const int lane = threadIdx.x & 63;
    const int wid = __builtin_amdgcn_readfirstlane(threadIdx.x >> 6);
    const int n = blockIdx.x * 4 + wid;
    if (n >= n_nodes) return;
    const int s = row_ptr[n];
    const int t = row_ptr[n + 1];
    float a0 = 0.0f, a1 = 0.0f, a2 = 0.0f, a3 = 0.0f;
    float inv = 0.0f;
    if (t > s) {
        // pass 1: segment max
        float m = -INFINITY;
        for (int base = s; base < t; base += WAVE) {
            int idx = base + lane;
            float a = (idx < t) ? att[idx] : -INFINITY;
            m = fmaxf(m, a);
        }
        m = wave_reduce_max(m);
        // pass 2: accumulate ex and ex-weighted src-feature rows
        float exsum = 0.0f;
        for (int base = s; base < t; base += WAVE) {
            int idx = base + lane;
            float ex = (idx < t) ? __expf(att[idx] - m) : 0.0f;
            int sv = (idx < t) ? src[idx] : 0;
            exsum += ex;
            int cnt = t - base;
            if (cnt > WAVE) cnt = WAVE;
            int cnt4 = (cnt + 3) & ~3;
            for (int j = 0; j < cnt4; j += 4) {
                float c0 = __shfl(ex, j + 0); int s0 = __shfl(sv, j + 0);
                float c1 = __shfl(ex, j + 1); int s1 = __shfl(sv, j + 1);
                float c2 = __shfl(ex, j + 2); int s2 = __shfl(sv, j + 2);
                float c3 = __shfl(ex, j + 3); int s3 = __shfl(sv, j + 3);
                a0 = fmaf(c0, nfeat[(size_t)s0 * D + lane], a0);
                a1 = fmaf(c1, nfeat[(size_t)s1 * D + lane], a1);
                a2 = fmaf(c2, nfeat[(size_t)s2 * D + lane], a2);
                a3 = fmaf(c3, nfeat[(size_t)s3 * D + lane], a3);
            }
        }
        float ssum = wave_reduce_sum(exsum);
        inv = 1.0f / ssum;
    }
    h_nb[(size_t)n * D + lane] = ((a0 + a1) + (a2 + a3)) * inv;
}

// ---------- 5. out = lrelu((x+h)W1^T) + lrelu((x*h)W2^T) ----------
// h_nb may ALIAS out (d_out used as scratch): each wave reads row n fully
// before writing row n -> safe; no __restrict__ on h/out.
__global__ __launch_bounds__(256) void out_kernel(
    const float* __restrict__ nfeat, const float* h_nb,
    const float* __restrict__ W1, const float* __restrict__ W2,
    float* out, int n_nodes) {
    const int lane = threadIdx.x & 63;
    const int wid = __builtin_amdgcn_readfirstlane(threadIdx.x >> 6);
    float w1[D], w2[D];
#pragma unroll
    for (int i = 0; i < D; ++i) w1[i] = W1[lane * D + i];
#pragma unroll
    for (int i = 0; i < D; ++i) w2[i] = W2[lane * D + i];
    const int nwaves = gridDim.x * 4;
    for (int n = blockIdx.x * 4 + wid; n < n_nodes; n += nwaves) {
        const int nn = __builtin_amdgcn_readfirstlane(n);
        const float* x = nfeat + (size_t)nn * D;  // uniform -> s_load
        const float* h = h_nb + (size_t)nn * D;
        float a0 = 0.0f, a1 = 0.0f, b0 = 0.0f, b1 = 0.0f;
#pragma unroll
        for (int i = 0; i < D; i += 2) {
            float x0 = x[i], h0 = h[i];
            float x1 = x[i + 1], h1 = h[i + 1];
            a0 = fmaf(x0 + h0, w1[i], a0);
            b0 = fmaf(x0 * h0, w2[i], b0);
            a1 = fmaf(x1 + h1, w1[i + 1], a1);
            b1 = fmaf(x1 * h1, w2[i + 1], b1);
        }
        float a = a0 + a1, b = b0 + b1;
        a = (a > 0.0f) ? a : 0.01f * a;
        b = (b > 0.0f) ? b : 0.01f * b;
        out[(size_t)nn * D + lane] = a + b;
    }
}

// ---------- launcher ----------
extern "C" void kernel_launch(void* const* d_in, const int* in_sizes, int n_in,
                              void* d_out, int out_size, void* d_ws, size_t ws_size,
                              hipStream_t stream) {
    const float* nfeat = (const float*)d_in[0];
    const float* efeat = (const float*)d_in[1];
    const float* relw  = (const float*)d_in[2];
    const float* w1    = (const float*)d_in[3];
    const float* w2    = (const float*)d_in[4];
    const int*   src   = (const int*)d_in[5];
    const int*   dst   = (const int*)d_in[6];
    const int*   etype = (const int*)d_in[7];
    float* out = (float*)d_out;

    const int n_nodes = in_sizes[0] / D;
    const int n_edges = in_sizes[5];
    const int n_rel   = in_sizes[2] / (D * D);

    const size_t ALIGN = 256;
    const size_t proj_bytes = ((size_t)n_nodes * n_rel * D * sizeof(__half) + ALIGN - 1) & ~(ALIGN - 1);
    const size_t att_bytes  = ((size_t)n_edges * sizeof(float) + ALIGN - 1) & ~(ALIGN - 1);

    // h_nb lives in d_out (out_kernel reads row n before writing row n).
    float* h_nb = out;

    char* ws = (char*)d_ws;
    __half* proj  = (__half*)ws;
    float* att    = (float*)(ws + proj_bytes);
    int* row_ptr  = (int*)(ws + proj_bytes + att_bytes);

    rowptr_kernel<<<1024, 256, 0, stream>>>(dst, row_ptr, n_edges, n_nodes);

    proj_kernel<<<(n_nodes + TILE - 1) / TILE, 256, 0, stream>>>(
        nfeat, relw, proj, n_nodes, n_rel);

    // 16 edges per block (4 waves x 4 edges)
    att_kernel<<<(n_edges + 15) / 16, 256, 0, stream>>>(proj, efeat, src, dst, etype,
                                                        att, n_edges, n_rel);

    agg_kernel<<<(n_nodes + 3) / 4, 256, 0, stream>>>(att, src, row_ptr, nfeat,
                                                      h_nb, n_nodes);

    out_kernel<<<1024, 256, 0, stream>>>(nfeat, h_nb, w1, w2, out, n_nodes);
}

// Round 7
// 695.444 us; speedup vs baseline: 1.2507x; 1.2507x over previous
//
#include <hip/hip_runtime.h>
#include <hip/hip_fp16.h>
#include <math.h>

#define D 64
#define WAVE 64

typedef _Float16 f16;
typedef f16 f16x8 __attribute__((ext_vector_type(8)));
typedef float f32x4 __attribute__((ext_vector_type(4)));

// ---------- helpers ----------
__device__ __forceinline__ float wave_reduce_sum(float v) {
    v += __shfl_xor(v, 32);
    v += __shfl_xor(v, 16);
    v += __shfl_xor(v, 8);
    v += __shfl_xor(v, 4);
    v += __shfl_xor(v, 2);
    v += __shfl_xor(v, 1);
    return v;
}

__device__ __forceinline__ float wave_reduce_max(float v) {
    v = fmaxf(v, __shfl_xor(v, 32));
    v = fmaxf(v, __shfl_xor(v, 16));
    v = fmaxf(v, __shfl_xor(v, 8));
    v = fmaxf(v, __shfl_xor(v, 4));
    v = fmaxf(v, __shfl_xor(v, 2));
    v = fmaxf(v, __shfl_xor(v, 1));
    return v;
}

__device__ __forceinline__ float fast_tanh(float x) {
    // tanh(x) = 1 - 2/(exp(2x)+1); saturates correctly at +-1 (inf-safe)
    float e = __expf(2.0f * x);
    return 1.0f - 2.0f / (e + 1.0f);
}

// ---------- 0. WT[r][o][k] = fp16(W[r][k][o]) ----------
// One-time 40K-element transpose+convert; B-operand then loads as contiguous
// 16B per lane from an 80KB L2-resident buffer (no per-block W staging).
__global__ void wt_kernel(const float* __restrict__ W, f16* __restrict__ WT,
                          int n_rel) {
    int idx = blockIdx.x * blockDim.x + threadIdx.x;
    if (idx >= n_rel * D * D) return;
    int r = idx >> 12;          // /4096
    int rem = idx & 4095;
    int o = rem >> 6;
    int k = rem & 63;
    WT[idx] = (f16)W[((size_t)r << 12) + (k << 6) + o];
}

// ---------- 1. proj[n][r][o] via MFMA (fp16 in, fp32 acc, fp16 out) ----------
// R5 post-mortem: VALU proj was latency-bound (Occ 15.9%, 292us). This is a
// matmul -> matrix cores. Block = 64-node A-tile staged fp32->fp16 in LDS
// once; A-frags hoisted to VGPRs and reused across ALL relations & col-tiles.
// Per relation: 8 B-loads (16B, L2-hot WT) + 8 mfma_f32_16x16x32_f16.
// A/B use the SAME within-lane k-map -> any HW k-permutation cancels.
// C/D layout (guide-verified): col = lane&15, row = (lane>>4)*4 + reg.
__global__ __launch_bounds__(256) void proj_kernel(
    const float* __restrict__ nfeat, const f16* __restrict__ WT,
    f16* __restrict__ proj, int n_nodes, int n_rel) {
    __shared__ f16 Al[64 * D];   // 8KB A-tile, row-major [row][k]
    const int tid = threadIdx.x;
    const int lane = tid & 63;
    const int wid = tid >> 6;
    const int n0 = blockIdx.x * 64;

    // stage A: 1024 float4 / 256 threads = 4 iters, fp32->fp16
    {
        const float4* g4 = (const float4*)(nfeat + (size_t)n0 * D);
        int avail_rows = n_nodes - n0;
        if (avail_rows > 64) avail_rows = 64;
        const int avail4 = avail_rows * (D / 4);
#pragma unroll
        for (int i = tid; i < 64 * (D / 4); i += 256) {
            float4 v = (i < avail4) ? g4[i] : make_float4(0.f, 0.f, 0.f, 0.f);
            f16* dp = &Al[i * 4];
            dp[0] = (f16)v.x; dp[1] = (f16)v.y; dp[2] = (f16)v.z; dp[3] = (f16)v.w;
        }
    }
    __syncthreads();

    const int g = lane >> 4;   // k-group 0..3
    const int c = lane & 15;   // col within 16-tile
    const int arow = wid * 16 + c;          // A-row for this lane (A: row=lane&15)
    f16x8 a0 = *(const f16x8*)&Al[arow * D + g * 8];        // k = g*8 .. +8
    f16x8 a1 = *(const f16x8*)&Al[arow * D + 32 + g * 8];   // k = 32+g*8 ..

    const int row_base = n0 + wid * 16 + g * 4;  // D-rows: row_base + j

    for (int r = 0; r < n_rel; ++r) {
        const f16* Wb = WT + ((size_t)r << 12);
        f32x4 acc[4] = {{0.f,0.f,0.f,0.f},{0.f,0.f,0.f,0.f},
                        {0.f,0.f,0.f,0.f},{0.f,0.f,0.f,0.f}};
#pragma unroll
        for (int t = 0; t < 4; ++t) {
            const f16* bp = Wb + (size_t)(t * 16 + c) * D + g * 8;
            f16x8 b0 = *(const f16x8*)bp;          // k = g*8..+8  (same map as A)
            f16x8 b1 = *(const f16x8*)(bp + 32);   // k = 32+g*8..
            acc[t] = __builtin_amdgcn_mfma_f32_16x16x32_f16(a0, b0, acc[t], 0, 0, 0);
            acc[t] = __builtin_amdgcn_mfma_f32_16x16x32_f16(a1, b1, acc[t], 0, 0, 0);
        }
        // direct stores: per (t,j) instr writes 4 rows x 32B segments; the 16
        // instrs fully cover 16 rows x 128B -> L2 merges to clean lines.
#pragma unroll
        for (int t = 0; t < 4; ++t) {
#pragma unroll
            for (int j = 0; j < 4; ++j) {
                int n = row_base + j;
                if (n < n_nodes)
                    proj[((size_t)n * n_rel + r) * D + t * 16 + c] = (f16)acc[t][j];
            }
        }
    }
}

// ---------- 2. att[e] = sum_d t_r[d] * tanh(h_r[d] + efeat[e][d]) ----------
// 4 edges per wave, 16 lanes per edge, 4 channels per lane:
// efeat via float4 (16B/lane), proj via 16B of halves, 4-step reduce.
__global__ __launch_bounds__(256) void att_kernel(
    const __half* __restrict__ proj, const float* __restrict__ efeat,
    const int* __restrict__ src, const int* __restrict__ dst,
    const int* __restrict__ etype, float* __restrict__ att,
    int n_edges, int n_rel) {
    const int lane = threadIdx.x & 63;
    const int wid = threadIdx.x >> 6;
    const int g = lane >> 4;       // edge slot 0..3 within wave
    const int c4 = lane & 15;      // float4 chunk of the row

    int e = (blockIdx.x * 4 + wid) * 4 + g;
    const bool valid = e < n_edges;
    const int ec = valid ? e : (n_edges - 1);
    const int s = src[ec];
    const int d = dst[ec];
    const int et = etype[ec];

    const float4* ef4 = (const float4*)(efeat + (size_t)ec * D);
    float4 ef = ef4[c4];
    const __half2* tp = (const __half2*)(proj + ((size_t)s * n_rel + et) * D) + c4 * 2;
    const __half2* hp = (const __half2*)(proj + ((size_t)d * n_rel + et) * D) + c4 * 2;
    float2 tA = __half22float2(tp[0]);
    float2 tB = __half22float2(tp[1]);
    float2 hA = __half22float2(hp[0]);
    float2 hB = __half22float2(hp[1]);

    float v = tA.x * fast_tanh(hA.x + ef.x)
            + tA.y * fast_tanh(hA.y + ef.y)
            + tB.x * fast_tanh(hB.x + ef.z)
            + tB.y * fast_tanh(hB.y + ef.w);
    v += __shfl_xor(v, 8);
    v += __shfl_xor(v, 4);
    v += __shfl_xor(v, 2);
    v += __shfl_xor(v, 1);
    if (valid && c4 == 0) att[e] = v;
}

// ---------- 3. CSR row_ptr from sorted dst ----------
__global__ void rowptr_kernel(const int* __restrict__ dst, int* __restrict__ row_ptr,
                              int n_edges, int n_nodes) {
    int tid = blockIdx.x * blockDim.x + threadIdx.x;
    int stride = gridDim.x * blockDim.x;
    for (int e = tid; e < n_edges; e += stride) {
        int d = dst[e];
        int dprev = (e == 0) ? -1 : dst[e - 1];
        for (int v = dprev + 1; v <= d; ++v) row_ptr[v] = e;
    }
    if (tid == 0) {
        int dlast = dst[n_edges - 1];
        for (int v = dlast + 1; v <= n_nodes; ++v) row_ptr[v] = n_edges;
    }
}

// ---------- 4. fused edge-softmax + weighted aggregation ----------
// Wave per node. h_nb[n] = (sum_j ex_j * nfeat[src_j]) / (sum_j ex_j).
// Inner j-loop unrolled x4 with 4 acc chains + 4 gathers in flight; padded
// lanes have ex=0 so no tail guards needed (fma adds 0).
__global__ __launch_bounds__(256) void agg_kernel(
    const float* __restrict__ att, const int* __restrict__ src,
    const int* __restrict__ row_ptr, const float* __restrict__ nfeat,
    float* __restrict__ h_nb, int n_nodes) {
    const int lane = threadIdx.x & 63;
    const int wid = __builtin_amdgcn_readfirstlane(threadIdx.x >> 6);
    const int n = blockIdx.x * 4 + wid;
    if (n >= n_nodes) return;
    const int s = row_ptr[n];
    const int t = row_ptr[n + 1];
    float a0 = 0.0f, a1 = 0.0f, a2 = 0.0f, a3 = 0.0f;
    float inv = 0.0f;
    if (t > s) {
        // pass 1: segment max
        float m = -INFINITY;
        for (int base = s; base < t; base += WAVE) {
            int idx = base + lane;
            float a = (idx < t) ? att[idx] : -INFINITY;
            m = fmaxf(m, a);
        }
        m = wave_reduce_max(m);
        // pass 2: accumulate ex and ex-weighted src-feature rows
        float exsum = 0.0f;
        for (int base = s; base < t; base += WAVE) {
            int idx = base + lane;
            float ex = (idx < t) ? __expf(att[idx] - m) : 0.0f;
            int sv = (idx < t) ? src[idx] : 0;
            exsum += ex;
            int cnt = t - base;
            if (cnt > WAVE) cnt = WAVE;
            int cnt4 = (cnt + 3) & ~3;
            for (int j = 0; j < cnt4; j += 4) {
                float c0 = __shfl(ex, j + 0); int s0 = __shfl(sv, j + 0);
                float c1 = __shfl(ex, j + 1); int s1 = __shfl(sv, j + 1);
                float c2 = __shfl(ex, j + 2); int s2 = __shfl(sv, j + 2);
                float c3 = __shfl(ex, j + 3); int s3 = __shfl(sv, j + 3);
                a0 = fmaf(c0, nfeat[(size_t)s0 * D + lane], a0);
                a1 = fmaf(c1, nfeat[(size_t)s1 * D + lane], a1);
                a2 = fmaf(c2, nfeat[(size_t)s2 * D + lane], a2);
                a3 = fmaf(c3, nfeat[(size_t)s3 * D + lane], a3);
            }
        }
        float ssum = wave_reduce_sum(exsum);
        inv = 1.0f / ssum;
    }
    h_nb[(size_t)n * D + lane] = ((a0 + a1) + (a2 + a3)) * inv;
}

// ---------- 5. out = lrelu((x+h)W1^T) + lrelu((x*h)W2^T) ----------
// h_nb may ALIAS out (d_out used as scratch): each wave reads row n fully
// before writing row n -> safe; no __restrict__ on h/out.
__global__ __launch_bounds__(256) void out_kernel(
    const float* __restrict__ nfeat, const float* h_nb,
    const float* __restrict__ W1, const float* __restrict__ W2,
    float* out, int n_nodes) {
    const int lane = threadIdx.x & 63;
    const int wid = __builtin_amdgcn_readfirstlane(threadIdx.x >> 6);
    float w1[D], w2[D];
#pragma unroll
    for (int i = 0; i < D; ++i) w1[i] = W1[lane * D + i];
#pragma unroll
    for (int i = 0; i < D; ++i) w2[i] = W2[lane * D + i];
    const int nwaves = gridDim.x * 4;
    for (int n = blockIdx.x * 4 + wid; n < n_nodes; n += nwaves) {
        const int nn = __builtin_amdgcn_readfirstlane(n);
        const float* x = nfeat + (size_t)nn * D;  // uniform -> s_load
        const float* h = h_nb + (size_t)nn * D;
        float a0 = 0.0f, a1 = 0.0f, b0 = 0.0f, b1 = 0.0f;
#pragma unroll
        for (int i = 0; i < D; i += 2) {
            float x0 = x[i], h0 = h[i];
            float x1 = x[i + 1], h1 = h[i + 1];
            a0 = fmaf(x0 + h0, w1[i], a0);
            b0 = fmaf(x0 * h0, w2[i], b0);
            a1 = fmaf(x1 + h1, w1[i + 1], a1);
            b1 = fmaf(x1 * h1, w2[i + 1], b1);
        }
        float a = a0 + a1, b = b0 + b1;
        a = (a > 0.0f) ? a : 0.01f * a;
        b = (b > 0.0f) ? b : 0.01f * b;
        out[(size_t)nn * D + lane] = a + b;
    }
}

// ---------- launcher ----------
extern "C" void kernel_launch(void* const* d_in, const int* in_sizes, int n_in,
                              void* d_out, int out_size, void* d_ws, size_t ws_size,
                              hipStream_t stream) {
    const float* nfeat = (const float*)d_in[0];
    const float* efeat = (const float*)d_in[1];
    const float* relw  = (const float*)d_in[2];
    const float* w1    = (const float*)d_in[3];
    const float* w2    = (const float*)d_in[4];
    const int*   src   = (const int*)d_in[5];
    const int*   dst   = (const int*)d_in[6];
    const int*   etype = (const int*)d_in[7];
    float* out = (float*)d_out;

    const int n_nodes = in_sizes[0] / D;
    const int n_edges = in_sizes[5];
    const int n_rel   = in_sizes[2] / (D * D);

    const size_t ALIGN = 256;
    const size_t proj_bytes = ((size_t)n_nodes * n_rel * D * sizeof(f16) + ALIGN - 1) & ~(ALIGN - 1);
    const size_t att_bytes  = ((size_t)n_edges * sizeof(float) + ALIGN - 1) & ~(ALIGN - 1);
    const size_t rp_bytes   = ((size_t)(n_nodes + 1) * sizeof(int) + ALIGN - 1) & ~(ALIGN - 1);

    // h_nb lives in d_out (out_kernel reads row n before writing row n).
    float* h_nb = out;

    char* ws = (char*)d_ws;
    f16*  proj    = (f16*)ws;
    float* att    = (float*)(ws + proj_bytes);
    int* row_ptr  = (int*)(ws + proj_bytes + att_bytes);
    f16*  wt      = (f16*)(ws + proj_bytes + att_bytes + rp_bytes);

    rowptr_kernel<<<1024, 256, 0, stream>>>(dst, row_ptr, n_edges, n_nodes);

    wt_kernel<<<(n_rel * D * D + 255) / 256, 256, 0, stream>>>(relw, wt, n_rel);

    proj_kernel<<<(n_nodes + 63) / 64, 256, 0, stream>>>(nfeat, wt, proj,
                                                         n_nodes, n_rel);

    // 16 edges per block (4 waves x 4 edges)
    att_kernel<<<(n_edges + 15) / 16, 256, 0, stream>>>((const __half*)proj, efeat,
                                                        src, dst, etype,
                                                        att, n_edges, n_rel);

    agg_kernel<<<(n_nodes + 3) / 4, 256, 0, stream>>>(att, src, row_ptr, nfeat,
                                                      h_nb, n_nodes);

    out_kernel<<<1024, 256, 0, stream>>>(nfeat, h_nb, w1, w2, out, n_nodes);
}

// Round 10
// 691.397 us; speedup vs baseline: 1.2580x; 1.0059x over previous
//
#include <hip/hip_runtime.h>
#include <hip/hip_fp16.h>
#include <math.h>

#define D 64
#define WAVE 64

typedef _Float16 f16;
typedef f16 f16x8 __attribute__((ext_vector_type(8)));
typedef float f32x4 __attribute__((ext_vector_type(4)));
typedef float fv4 __attribute__((ext_vector_type(4)));  // clang vec: ok for __builtin_nontemporal_load

// ---------- helpers ----------
__device__ __forceinline__ float wave_reduce_sum(float v) {
    v += __shfl_xor(v, 32);
    v += __shfl_xor(v, 16);
    v += __shfl_xor(v, 8);
    v += __shfl_xor(v, 4);
    v += __shfl_xor(v, 2);
    v += __shfl_xor(v, 1);
    return v;
}

__device__ __forceinline__ float wave_reduce_max(float v) {
    v = fmaxf(v, __shfl_xor(v, 32));
    v = fmaxf(v, __shfl_xor(v, 16));
    v = fmaxf(v, __shfl_xor(v, 8));
    v = fmaxf(v, __shfl_xor(v, 4));
    v = fmaxf(v, __shfl_xor(v, 2));
    v = fmaxf(v, __shfl_xor(v, 1));
    return v;
}

__device__ __forceinline__ float fast_tanh(float x) {
    // tanh(x) = 1 - 2/(exp(2x)+1); saturates correctly at +-1 (inf-safe)
    float e = __expf(2.0f * x);
    return 1.0f - 2.0f / (e + 1.0f);
}

// ---------- 0. WT[r][o][k] = fp16(W[r][k][o]) ----------
__global__ void wt_kernel(const float* __restrict__ W, f16* __restrict__ WT,
                          int n_rel) {
    int idx = blockIdx.x * blockDim.x + threadIdx.x;
    if (idx >= n_rel * D * D) return;
    int r = idx >> 12;          // /4096
    int rem = idx & 4095;
    int o = rem >> 6;
    int k = rem & 63;
    WT[idx] = (f16)W[((size_t)r << 12) + (k << 6) + o];
}

// ---------- 1. proj[n][r][o] via MFMA (fp16 in, fp32 acc, fp16 out) ----------
// (R7: MFMA proj confirmed, 870->695us total.) Also spills the fp16-converted
// nfeat tile to nf16[] so agg can gather 2B/elem instead of 4B.
__global__ __launch_bounds__(256) void proj_kernel(
    const float* __restrict__ nfeat, const f16* __restrict__ WT,
    f16* __restrict__ proj, f16* __restrict__ nf16, int n_nodes, int n_rel) {
    __shared__ f16 Al[64 * D];   // 8KB A-tile, row-major [row][k]
    const int tid = threadIdx.x;
    const int lane = tid & 63;
    const int wid = tid >> 6;
    const int n0 = blockIdx.x * 64;

    // stage A: 1024 float4 / 256 threads = 4 iters, fp32->fp16 (+ global spill)
    {
        const float4* g4 = (const float4*)(nfeat + (size_t)n0 * D);
        int avail_rows = n_nodes - n0;
        if (avail_rows > 64) avail_rows = 64;
        const int avail4 = avail_rows * (D / 4);
#pragma unroll
        for (int i = tid; i < 64 * (D / 4); i += 256) {
            float4 v = (i < avail4) ? g4[i] : make_float4(0.f, 0.f, 0.f, 0.f);
            f16 h0 = (f16)v.x, h1 = (f16)v.y, h2 = (f16)v.z, h3 = (f16)v.w;
            f16* dp = &Al[i * 4];
            dp[0] = h0; dp[1] = h1; dp[2] = h2; dp[3] = h3;
            if (i < avail4) {
                f16* np = nf16 + (size_t)n0 * D + i * 4;
                np[0] = h0; np[1] = h1; np[2] = h2; np[3] = h3;
            }
        }
    }
    __syncthreads();

    const int g = lane >> 4;   // k-group 0..3
    const int c = lane & 15;   // col within 16-tile
    const int arow = wid * 16 + c;
    f16x8 a0 = *(const f16x8*)&Al[arow * D + g * 8];
    f16x8 a1 = *(const f16x8*)&Al[arow * D + 32 + g * 8];

    const int row_base = n0 + wid * 16 + g * 4;

    for (int r = 0; r < n_rel; ++r) {
        const f16* Wb = WT + ((size_t)r << 12);
        f32x4 acc[4] = {{0.f,0.f,0.f,0.f},{0.f,0.f,0.f,0.f},
                        {0.f,0.f,0.f,0.f},{0.f,0.f,0.f,0.f}};
#pragma unroll
        for (int t = 0; t < 4; ++t) {
            const f16* bp = Wb + (size_t)(t * 16 + c) * D + g * 8;
            f16x8 b0 = *(const f16x8*)bp;
            f16x8 b1 = *(const f16x8*)(bp + 32);
            acc[t] = __builtin_amdgcn_mfma_f32_16x16x32_f16(a0, b0, acc[t], 0, 0, 0);
            acc[t] = __builtin_amdgcn_mfma_f32_16x16x32_f16(a1, b1, acc[t], 0, 0, 0);
        }
#pragma unroll
        for (int t = 0; t < 4; ++t) {
#pragma unroll
            for (int j = 0; j < 4; ++j) {
                int n = row_base + j;
                if (n < n_nodes)
                    proj[((size_t)n * n_rel + r) * D + t * 16 + c] = (f16)acc[t][j];
            }
        }
    }
}

// ---------- 2. att[e] = sum_d t_r[d] * tanh(h_r[d] + efeat[e][d]) ----------
// R2 counters: 1.8 TB/s, latency-bound. Now 8 edges/wave (16-lane group
// pipelines 2 edges -> 2x loads in flight) + NON-TEMPORAL efeat stream
// (visited once; keeps proj L3-resident for the gathers).
__global__ __launch_bounds__(256) void att_kernel(
    const __half* __restrict__ proj, const float* __restrict__ efeat,
    const int* __restrict__ src, const int* __restrict__ dst,
    const int* __restrict__ etype, float* __restrict__ att,
    int n_edges, int n_rel) {
    const int lane = threadIdx.x & 63;
    const int wid = threadIdx.x >> 6;
    const int g = lane >> 4;       // edge slot 0..3 within wave
    const int c4 = lane & 15;      // float4 chunk of the row

    const int eb = (blockIdx.x * 4 + wid) * 8 + g;
    const int e0 = eb, e1 = eb + 4;
    const bool v0 = e0 < n_edges, v1 = e1 < n_edges;
    const int ec0 = v0 ? e0 : (n_edges - 1);
    const int ec1 = v1 ? e1 : (n_edges - 1);
    const int s0 = src[ec0], d0 = dst[ec0], t0 = etype[ec0];
    const int s1 = src[ec1], d1 = dst[ec1], t1 = etype[ec1];

    // issue all 6 row loads before any compute (MLP)
    fv4 ef0 = __builtin_nontemporal_load((const fv4*)(efeat + (size_t)ec0 * D) + c4);
    fv4 ef1 = __builtin_nontemporal_load((const fv4*)(efeat + (size_t)ec1 * D) + c4);
    const __half2* tp0 = (const __half2*)(proj + ((size_t)s0 * n_rel + t0) * D) + c4 * 2;
    const __half2* hp0 = (const __half2*)(proj + ((size_t)d0 * n_rel + t0) * D) + c4 * 2;
    const __half2* tp1 = (const __half2*)(proj + ((size_t)s1 * n_rel + t1) * D) + c4 * 2;
    const __half2* hp1 = (const __half2*)(proj + ((size_t)d1 * n_rel + t1) * D) + c4 * 2;
    float2 tA0 = __half22float2(tp0[0]), tB0 = __half22float2(tp0[1]);
    float2 hA0 = __half22float2(hp0[0]), hB0 = __half22float2(hp0[1]);
    float2 tA1 = __half22float2(tp1[0]), tB1 = __half22float2(tp1[1]);
    float2 hA1 = __half22float2(hp1[0]), hB1 = __half22float2(hp1[1]);

    float r0 = tA0.x * fast_tanh(hA0.x + ef0.x)
             + tA0.y * fast_tanh(hA0.y + ef0.y)
             + tB0.x * fast_tanh(hB0.x + ef0.z)
             + tB0.y * fast_tanh(hB0.y + ef0.w);
    float r1 = tA1.x * fast_tanh(hA1.x + ef1.x)
             + tA1.y * fast_tanh(hA1.y + ef1.y)
             + tB1.x * fast_tanh(hB1.x + ef1.z)
             + tB1.y * fast_tanh(hB1.y + ef1.w);
    r0 += __shfl_xor(r0, 8); r1 += __shfl_xor(r1, 8);
    r0 += __shfl_xor(r0, 4); r1 += __shfl_xor(r1, 4);
    r0 += __shfl_xor(r0, 2); r1 += __shfl_xor(r1, 2);
    r0 += __shfl_xor(r0, 1); r1 += __shfl_xor(r1, 1);
    if (c4 == 0) {
        if (v0) att[e0] = r0;
        if (v1) att[e1] = r1;
    }
}

// ---------- 3. CSR row_ptr from sorted dst ----------
__global__ void rowptr_kernel(const int* __restrict__ dst, int* __restrict__ row_ptr,
                              int n_edges, int n_nodes) {
    int tid = blockIdx.x * blockDim.x + threadIdx.x;
    int stride = gridDim.x * blockDim.x;
    for (int e = tid; e < n_edges; e += stride) {
        int d = dst[e];
        int dprev = (e == 0) ? -1 : dst[e - 1];
        for (int v = dprev + 1; v <= d; ++v) row_ptr[v] = e;
    }
    if (tid == 0) {
        int dlast = dst[n_edges - 1];
        for (int v = dlast + 1; v <= n_nodes; ++v) row_ptr[v] = n_edges;
    }
}

// ---------- 4. fused edge-softmax + weighted aggregation ----------
// Wave per node; gathers from the fp16 nfeat copy (2B/elem, hotter in L2/L3).
// Inner loop unrolled x8 -> 8 gathers in flight; padded lanes ex=0.
__global__ __launch_bounds__(256) void agg_kernel(
    const float* __restrict__ att, const int* __restrict__ src,
    const int* __restrict__ row_ptr, const f16* __restrict__ nf16,
    float* __restrict__ h_nb, int n_nodes) {
    const int lane = threadIdx.x & 63;
    const int wid = __builtin_amdgcn_readfirstlane(threadIdx.x >> 6);
    const int n = blockIdx.x * 4 + wid;
    if (n >= n_nodes) return;
    const int s = row_ptr[n];
    const int t = row_ptr[n + 1];
    float a0 = 0.f, a1 = 0.f, a2 = 0.f, a3 = 0.f;
    float a4 = 0.f, a5 = 0.f, a6 = 0.f, a7 = 0.f;
    float inv = 0.0f;
    if (t > s) {
        // pass 1: segment max
        float m = -INFINITY;
        for (int base = s; base < t; base += WAVE) {
            int idx = base + lane;
            float a = (idx < t) ? att[idx] : -INFINITY;
            m = fmaxf(m, a);
        }
        m = wave_reduce_max(m);
        // pass 2: accumulate ex and ex-weighted src-feature rows
        float exsum = 0.0f;
        for (int base = s; base < t; base += WAVE) {
            int idx = base + lane;
            float ex = (idx < t) ? __expf(att[idx] - m) : 0.0f;
            int sv = (idx < t) ? src[idx] : 0;
            exsum += ex;
            int cnt = t - base;
            if (cnt > WAVE) cnt = WAVE;
            int cnt8 = (cnt + 7) & ~7;
            for (int j = 0; j < cnt8; j += 8) {
                float c0 = __shfl(ex, j + 0); int s0 = __shfl(sv, j + 0);
                float c1 = __shfl(ex, j + 1); int s1 = __shfl(sv, j + 1);
                float c2 = __shfl(ex, j + 2); int s2 = __shfl(sv, j + 2);
                float c3 = __shfl(ex, j + 3); int s3 = __shfl(sv, j + 3);
                float c4 = __shfl(ex, j + 4); int s4 = __shfl(sv, j + 4);
                float c5 = __shfl(ex, j + 5); int s5 = __shfl(sv, j + 5);
                float c6 = __shfl(ex, j + 6); int s6 = __shfl(sv, j + 6);
                float c7 = __shfl(ex, j + 7); int s7 = __shfl(sv, j + 7);
                a0 = fmaf(c0, (float)nf16[(size_t)s0 * D + lane], a0);
                a1 = fmaf(c1, (float)nf16[(size_t)s1 * D + lane], a1);
                a2 = fmaf(c2, (float)nf16[(size_t)s2 * D + lane], a2);
                a3 = fmaf(c3, (float)nf16[(size_t)s3 * D + lane], a3);
                a4 = fmaf(c4, (float)nf16[(size_t)s4 * D + lane], a4);
                a5 = fmaf(c5, (float)nf16[(size_t)s5 * D + lane], a5);
                a6 = fmaf(c6, (float)nf16[(size_t)s6 * D + lane], a6);
                a7 = fmaf(c7, (float)nf16[(size_t)s7 * D + lane], a7);
            }
        }
        float ssum = wave_reduce_sum(exsum);
        inv = 1.0f / ssum;
    }
    h_nb[(size_t)n * D + lane] =
        (((a0 + a1) + (a2 + a3)) + ((a4 + a5) + (a6 + a7))) * inv;
}

// ---------- 5. out = lrelu((x+h)W1^T) + lrelu((x*h)W2^T) ----------
// h_nb ALIASES out: each wave reads row n fully before writing row n -> safe.
__global__ __launch_bounds__(256) void out_kernel(
    const float* __restrict__ nfeat, const float* h_nb,
    const float* __restrict__ W1, const float* __restrict__ W2,
    float* out, int n_nodes) {
    const int lane = threadIdx.x & 63;
    const int wid = __builtin_amdgcn_readfirstlane(threadIdx.x >> 6);
    float w1[D], w2[D];
#pragma unroll
    for (int i = 0; i < D; ++i) w1[i] = W1[lane * D + i];
#pragma unroll
    for (int i = 0; i < D; ++i) w2[i] = W2[lane * D + i];
    const int nwaves = gridDim.x * 4;
    for (int n = blockIdx.x * 4 + wid; n < n_nodes; n += nwaves) {
        const int nn = __builtin_amdgcn_readfirstlane(n);
        const float* x = nfeat + (size_t)nn * D;  // uniform -> s_load
        const float* h = h_nb + (size_t)nn * D;
        float a0 = 0.0f, a1 = 0.0f, b0 = 0.0f, b1 = 0.0f;
#pragma unroll
        for (int i = 0; i < D; i += 2) {
            float x0 = x[i], h0 = h[i];
            float x1 = x[i + 1], h1 = h[i + 1];
            a0 = fmaf(x0 + h0, w1[i], a0);
            b0 = fmaf(x0 * h0, w2[i], b0);
            a1 = fmaf(x1 + h1, w1[i + 1], a1);
            b1 = fmaf(x1 * h1, w2[i + 1], b1);
        }
        float a = a0 + a1, b = b0 + b1;
        a = (a > 0.0f) ? a : 0.01f * a;
        b = (b > 0.0f) ? b : 0.01f * b;
        out[(size_t)nn * D + lane] = a + b;
    }
}

// ---------- launcher ----------
extern "C" void kernel_launch(void* const* d_in, const int* in_sizes, int n_in,
                              void* d_out, int out_size, void* d_ws, size_t ws_size,
                              hipStream_t stream) {
    const float* nfeat = (const float*)d_in[0];
    const float* efeat = (const float*)d_in[1];
    const float* relw  = (const float*)d_in[2];
    const float* w1    = (const float*)d_in[3];
    const float* w2    = (const float*)d_in[4];
    const int*   src   = (const int*)d_in[5];
    const int*   dst   = (const int*)d_in[6];
    const int*   etype = (const int*)d_in[7];
    float* out = (float*)d_out;

    const int n_nodes = in_sizes[0] / D;
    const int n_edges = in_sizes[5];
    const int n_rel   = in_sizes[2] / (D * D);

    const size_t ALIGN = 256;
    const size_t proj_bytes = ((size_t)n_nodes * n_rel * D * sizeof(f16) + ALIGN - 1) & ~(ALIGN - 1);
    const size_t att_bytes  = ((size_t)n_edges * sizeof(float) + ALIGN - 1) & ~(ALIGN - 1);
    const size_t rp_bytes   = ((size_t)(n_nodes + 1) * sizeof(int) + ALIGN - 1) & ~(ALIGN - 1);
    const size_t wt_bytes   = ((size_t)n_rel * D * D * sizeof(f16) + ALIGN - 1) & ~(ALIGN - 1);

    // h_nb lives in d_out (out_kernel reads row n before writing row n).
    float* h_nb = out;

    char* ws = (char*)d_ws;
    f16*  proj    = (f16*)ws;
    float* att    = (float*)(ws + proj_bytes);
    int* row_ptr  = (int*)(ws + proj_bytes + att_bytes);
    f16*  wt      = (f16*)(ws + proj_bytes + att_bytes + rp_bytes);
    f16*  nf16    = (f16*)(ws + proj_bytes + att_bytes + rp_bytes + wt_bytes);

    rowptr_kernel<<<1024, 256, 0, stream>>>(dst, row_ptr, n_edges, n_nodes);

    wt_kernel<<<(n_rel * D * D + 255) / 256, 256, 0, stream>>>(relw, wt, n_rel);

    proj_kernel<<<(n_nodes + 63) / 64, 256, 0, stream>>>(nfeat, wt, proj, nf16,
                                                         n_nodes, n_rel);

    // 32 edges per block (4 waves x 8 edges)
    att_kernel<<<(n_edges + 31) / 32, 256, 0, stream>>>((const __half*)proj, efeat,
                                                        src, dst, etype,
                                                        att, n_edges, n_rel);

    agg_kernel<<<(n_nodes + 3) / 4, 256, 0, stream>>>(att, src, row_ptr, nf16,
                                                      h_nb, n_nodes);

    out_kernel<<<3200, 256, 0, stream>>>(nfeat, h_nb, w1, w2, out, n_nodes);
}